// Round 6
// baseline (226.275 us; speedup 1.0000x reference)
//
#include <hip/hip_runtime.h>

#define NT 256
#define GMAXN 1536          // max group size (NMAX)
#define SLOT 6              // GMAXN / NT
#define TVITERS 20
#define BISECT 14
#define BMAX 4096

__device__ int g_off[BMAX];
__device__ int g_maxdeg;

// K1: exclusive scan of sizes -> g_off, zero g_maxdeg. One block.
__global__ __launch_bounds__(NT) void k_scan(const int* __restrict__ sizes, int B) {
  __shared__ int part[NT];
  int t = threadIdx.x;
  int per = (B + NT - 1) / NT;
  int base = t * per;
  int acc = 0;
  for (int k = 0; k < per; ++k) {
    int i = base + k;
    if (i < B) acc += sizes[i];
  }
  part[t] = acc;
  __syncthreads();
  if (t == 0) {
    int run = 0;
    for (int i = 0; i < NT; ++i) { int tmp = part[i]; part[i] = run; run += tmp; }
    g_maxdeg = 0;
  }
  __syncthreads();
  int run = part[t];
  for (int k = 0; k < per; ++k) {
    int i = base + k;
    if (i < B) { g_off[i] = run; run += sizes[i]; }
  }
}

// K2: per-group max degree -> global atomicMax. Chain part analytic.
__global__ __launch_bounds__(NT) void k_deg(const int* __restrict__ sizes,
                                            const int* __restrict__ edges,
                                            int N, int B) {
  __shared__ int cnt[GMAXN];
  __shared__ int wred[4];
  int g = blockIdx.x;
  int t = threadIdx.x;
  int s = sizes[g];
  int off = g_off[g];
  for (int i = t; i < s; i += NT)
    cnt[i] = 2 - (i == 0 ? 1 : 0) - (i == s - 1 ? 1 : 0);
  __syncthreads();
  const int2* re2 = (const int2*)(edges) + (N - B) + off;
  for (int j = t; j < s; j += NT) {
    int2 e = re2[j];
    atomicAdd(&cnt[e.x - off], 1);
    atomicAdd(&cnt[e.y - off], 1);
  }
  __syncthreads();
  int m = 0;
  for (int i = t; i < s; i += NT) m = max(m, cnt[i]);
  #pragma unroll
  for (int o = 32; o > 0; o >>= 1) m = max(m, __shfl_down(m, o, 64));
  if ((t & 63) == 0) wred[t >> 6] = m;
  __syncthreads();
  if (t == 0) {
    m = max(max(wred[0], wred[1]), max(wred[2], wred[3]));
    atomicMax(&g_maxdeg, m);
  }
}

// K3: one block per group. Node-centric duplicated-u ("v" trick): every
// incident edge's u is kept (sign-local) at BOTH endpoints; duplicates stay
// bit-exactly negated, so no cross-thread u communication is needed. y is
// double-buffered in LDS -> ONE barrier per TV iteration, zero atomics.
// First two CSR entries per node cached in registers (index + v).
__global__ __launch_bounds__(NT, 5) void k_main(const float* __restrict__ x,
                                                const int* __restrict__ sizes,
                                                const int* __restrict__ edges,
                                                float* __restrict__ out,
                                                int N, int B) {
  __shared__ float yA[GMAXN];          // hosts int cnt[] during build
  __shared__ float yB[GMAXN];          // hosts ushort offL[GMAXN+1] during build
  __shared__ float uD[2 * GMAXN];      // overflow v entries; hosts int cur[] in build
  __shared__ ushort entL[2 * GMAXN];   // CSR entries: other-endpoint index
  __shared__ float redf[2][4];
  __shared__ float2 red2[4];
  __shared__ int wtot[4];

  int g = blockIdx.x;
  int t = threadIdx.x;
  int lane = t & 63, wid = t >> 6;
  int s = sizes[g];
  int off = g_off[g];
  const int2* re2 = (const int2*)(edges) + (N - B) + off;
  float step = 1.0f / (2.0f * (float)g_maxdeg);

  int* cnt = (int*)yA;
  ushort* offL = (ushort*)yB;
  int* cur = (int*)uD;

  // ---- CSR build (random edges only) ----
  #pragma unroll
  for (int k = 0; k < SLOT; ++k) { int i = t + k * NT; if (i < s) cnt[i] = 0; }
  __syncthreads();
  uint ab[SLOT];
  #pragma unroll
  for (int k = 0; k < SLOT; ++k) {
    int j = t + k * NT;
    uint pk = 0;
    if (j < s) {
      int2 e = re2[j];
      int a = e.x - off, b2 = e.y - off;
      pk = (uint)a | ((uint)b2 << 16);
      atomicAdd(&cnt[a], 1);
      atomicAdd(&cnt[b2], 1);
    }
    ab[k] = pk;
  }
  __syncthreads();
  // chunked exclusive scan: thread t owns nodes [t*SLOT, t*SLOT+SLOT)
  int c[SLOT];
  int tot = 0;
  #pragma unroll
  for (int k = 0; k < SLOT; ++k) {
    int i = t * SLOT + k;
    int v = (i < s) ? cnt[i] : 0;
    c[k] = tot; tot += v;
  }
  int inc = tot;
  #pragma unroll
  for (int o = 1; o < 64; o <<= 1) {
    int n = __shfl_up(inc, o, 64);
    if (lane >= o) inc += n;
  }
  if (lane == 63) wtot[wid] = inc;
  __syncthreads();
  int wpre = 0;
  #pragma unroll
  for (int w = 0; w < 4; ++w) wpre += (w < wid) ? wtot[w] : 0;
  int basep = wpre + (inc - tot);
  #pragma unroll
  for (int k = 0; k < SLOT; ++k) {
    int i = t * SLOT + k;
    if (i < s) { int v = basep + c[k]; offL[i] = (ushort)v; cur[i] = v; }
  }
  if (t == 0) offL[s] = (ushort)(2 * s);
  __syncthreads();
  // fill entries (other-endpoint index; no signs needed with v-trick)
  #pragma unroll
  for (int k = 0; k < SLOT; ++k) {
    int j = t + k * NT;
    if (j < s) {
      int a = (int)(ab[k] & 0xFFFFu);
      int b2 = (int)(ab[k] >> 16);
      int p = atomicAdd(&cur[a], 1);
      entL[p] = (ushort)b2;
      p = atomicAdd(&cur[b2], 1);
      entL[p] = (ushort)a;
    }
  }
  __syncthreads();

  // ---- hoist CSR ranges + first-2 entries; load x; init state ----
  uint pq[SLOT], e01[SLOT];
  float xr[SLOT], yreg[SLOT], vL[SLOT], vR[SLOT], v0[SLOT], v1[SLOT];
  #pragma unroll
  for (int k = 0; k < SLOT; ++k) {
    int i = t + k * NT;
    vL[k] = vR[k] = v0[k] = v1[k] = 0.0f;
    uint pk = 0, e = 0;
    float xv = 0.0f;
    if (i < s) {
      uint p0 = offL[i];
      uint n = (uint)offL[i + 1] - p0;
      pk = p0 | (n << 16);
      uint e0 = (n >= 1) ? (uint)entL[p0] : 0u;
      uint e1 = (n >= 2) ? (uint)entL[p0 + 1] : 0u;
      e = e0 | (e1 << 16);
      xv = x[off + i];
    }
    pq[k] = pk; e01[k] = e; xr[k] = xv;
    yreg[k] = (i < s) ? xv : -1e30f;
  }
  // zero overflow-v storage (overwrites cur), init yA = x (overwrites cnt)
  #pragma unroll
  for (int k = 0; k < 2 * SLOT; ++k) { int p = t + k * NT; if (p < 2 * s) uD[p] = 0.0f; }
  #pragma unroll
  for (int k = 0; k < SLOT; ++k) { int i = t + k * NT; if (i < s) yA[i] = xr[k]; }
  __syncthreads();

  // ---- TV iterations: ONE barrier each ----
  float* yIn = yA;
  float* yOut = yB;
  for (int it = 0; it < TVITERS; ++it) {
    // batched reads (clamped addresses, predicated use -> full MLP)
    float yp[SLOT], yn[SLOT], yo0[SLOT], yo1[SLOT];
    #pragma unroll
    for (int k = 0; k < SLOT; ++k) {
      int i = t + k * NT;
      int im = (i > 0) ? i - 1 : 0;
      int ip = (i + 1 < s) ? i + 1 : 0;
      yp[k] = yIn[im];
      yn[k] = yIn[ip];
      yo0[k] = yIn[e01[k] & 0xFFFFu];
      yo1[k] = yIn[e01[k] >> 16];
    }
    #pragma unroll
    for (int k = 0; k < SLOT; ++k) {
      int i = t + k * NT;
      if (i < s) {
        float yi = yreg[k];
        float a = 0.0f;
        if (i > 0) {
          float v = vL[k] + step * (yi - yp[k]);
          v = fminf(1.0f, fmaxf(-1.0f, v));
          vL[k] = v; a += v;
        }
        if (i + 1 < s) {
          float v = vR[k] + step * (yi - yn[k]);
          v = fminf(1.0f, fmaxf(-1.0f, v));
          vR[k] = v; a += v;
        }
        uint n = pq[k] >> 16;
        if (n >= 1) {
          float v = v0[k] + step * (yi - yo0[k]);
          v = fminf(1.0f, fmaxf(-1.0f, v));
          v0[k] = v; a += v;
        }
        if (n >= 2) {
          float v = v1[k] + step * (yi - yo1[k]);
          v = fminf(1.0f, fmaxf(-1.0f, v));
          v1[k] = v; a += v;
        }
        uint p0 = pq[k] & 0xFFFFu;
        for (uint q = 2; q < n; ++q) {
          int o2 = entL[p0 + q];
          float yo = yIn[o2];
          float v = uD[p0 + q];
          v = fminf(1.0f, fmaxf(-1.0f, v + step * (yi - yo)));
          uD[p0 + q] = v;
          a += v;
        }
        float ynew = xr[k] - a;
        yreg[k] = ynew;
        if (it < TVITERS - 1) yOut[i] = ynew;
      }
    }
    if (it < TVITERS - 1) __syncthreads();
    float* tmp = yIn; yIn = yOut; yOut = tmp;
  }

  // ---- sparsemax on z = yreg (GAMMA = 1) ----
  float m = -1e30f;
  #pragma unroll
  for (int k = 0; k < SLOT; ++k) m = fmaxf(m, yreg[k]);
  #pragma unroll
  for (int o = 1; o < 64; o <<= 1) m = fmaxf(m, __shfl_xor(m, o, 64));
  if (lane == 0) redf[0][wid] = m;
  __syncthreads();
  m = fmaxf(fmaxf(redf[0][0], redf[0][1]), fmaxf(redf[0][2], redf[0][3]));

  float lo = m - 1.0f, hi = m;
  int par = 1;
  for (int r = 0; r < BISECT; ++r) {
    float mid = 0.5f * (lo + hi);
    float f = 0.0f;
    #pragma unroll
    for (int k = 0; k < SLOT; ++k) f += fmaxf(yreg[k] - mid, 0.0f);
    #pragma unroll
    for (int o = 1; o < 64; o <<= 1) f += __shfl_xor(f, o, 64);
    if (lane == 0) redf[par][wid] = f;
    __syncthreads();
    f = (redf[par][0] + redf[par][1]) + (redf[par][2] + redf[par][3]);
    par ^= 1;
    if (f >= 1.0f) lo = mid; else hi = mid;
  }
  // exact refinement on identified support
  float cf = 0.0f, S = 0.0f;
  #pragma unroll
  for (int k = 0; k < SLOT; ++k) {
    if (yreg[k] > lo) { cf += 1.0f; S += yreg[k]; }
  }
  #pragma unroll
  for (int o = 1; o < 64; o <<= 1) {
    cf += __shfl_xor(cf, o, 64);
    S += __shfl_xor(S, o, 64);
  }
  if (lane == 0) red2[wid] = make_float2(cf, S);
  __syncthreads();
  cf = (red2[0].x + red2[1].x) + (red2[2].x + red2[3].x);
  S  = (red2[0].y + red2[1].y) + (red2[2].y + red2[3].y);
  float tau = (S - 1.0f) / cf;

  float sf = (float)s;
  float* og = out + off;
  #pragma unroll
  for (int k = 0; k < SLOT; ++k) {
    int i = t + k * NT;
    if (i < s) og[i] = fmaxf(yreg[k] - tau, 0.0f) * sf;
  }
}

extern "C" void kernel_launch(void* const* d_in, const int* in_sizes, int n_in,
                              void* d_out, int out_size, void* d_ws, size_t ws_size,
                              hipStream_t stream) {
  const float* x = (const float*)d_in[0];
  const int* sizes = (const int*)d_in[1];
  const int* edges = (const int*)d_in[2];
  float* out = (float*)d_out;
  int N = in_sizes[0];
  int B = in_sizes[1];
  (void)d_ws; (void)ws_size; (void)n_in; (void)out_size;

  k_scan<<<1, NT, 0, stream>>>(sizes, B);
  k_deg<<<B, NT, 0, stream>>>(sizes, edges, N, B);
  k_main<<<B, NT, 0, stream>>>(x, sizes, edges, out, N, B);
}

// Round 7
// 185.661 us; speedup vs baseline: 1.2188x; 1.2188x over previous
//
#include <hip/hip_runtime.h>

#define NT 256
#define CAP 2064            // max union size per block (rank-pair sums = 2048/2049)
#define SLOT 9              // ceil(CAP/NT)
#define GMAXN 1536          // max single group size
#define TVITERS 20
#define BISECT 14
#define BMAX 4096
#define NBIN 1025           // size bins: sizes-512 in [0,1024]

__device__ int g_off[BMAX];
__device__ int g_rank[BMAX];
__device__ int g_maxdeg;

// K1: exclusive scan of sizes -> g_off; counting-sort by size -> g_rank.
__global__ __launch_bounds__(NT) void k_scan(const int* __restrict__ sizes, int B) {
  __shared__ int part[NT];
  __shared__ int histC[NBIN];
  __shared__ int histO[NBIN];
  __shared__ int wtot[4];
  int t = threadIdx.x;
  int lane = t & 63, wid = t >> 6;

  // ---- offsets
  int per = (B + NT - 1) / NT;
  int base = t * per;
  int acc = 0;
  for (int k = 0; k < per; ++k) {
    int i = base + k;
    if (i < B) acc += sizes[i];
  }
  part[t] = acc;
  __syncthreads();
  if (t == 0) {
    int run = 0;
    for (int i = 0; i < NT; ++i) { int tmp = part[i]; part[i] = run; run += tmp; }
    g_maxdeg = 0;
  }
  __syncthreads();
  int run = part[t];
  for (int k = 0; k < per; ++k) {
    int i = base + k;
    if (i < B) { g_off[i] = run; run += sizes[i]; }
  }

  // ---- counting sort by size
  for (int i = t; i < NBIN; i += NT) histC[i] = 0;
  __syncthreads();
  for (int i = t; i < B; i += NT) atomicAdd(&histC[sizes[i] - 512], 1);
  __syncthreads();
  // chunked exclusive scan of histC (5 bins per thread covers 1280 >= 1025)
  int c[5];
  int tot = 0;
  #pragma unroll
  for (int k = 0; k < 5; ++k) {
    int i = t * 5 + k;
    int v = (i < NBIN) ? histC[i] : 0;
    c[k] = tot; tot += v;
  }
  int inc = tot;
  #pragma unroll
  for (int o = 1; o < 64; o <<= 1) {
    int n = __shfl_up(inc, o, 64);
    if (lane >= o) inc += n;
  }
  if (lane == 63) wtot[wid] = inc;
  __syncthreads();
  int wpre = 0;
  #pragma unroll
  for (int w = 0; w < 4; ++w) wpre += (w < wid) ? wtot[w] : 0;
  int basep = wpre + (inc - tot);
  #pragma unroll
  for (int k = 0; k < 5; ++k) {
    int i = t * 5 + k;
    if (i < NBIN) histO[i] = basep + c[k];
  }
  __syncthreads();
  // scatter ranks
  for (int i = t; i < B; i += NT) {
    int r = atomicAdd(&histO[sizes[i] - 512], 1);
    g_rank[r] = i;
  }
}

// K2: per-group max degree -> global atomicMax. Chain part analytic.
__global__ __launch_bounds__(NT) void k_deg(const int* __restrict__ sizes,
                                            const int* __restrict__ edges,
                                            int N, int B) {
  __shared__ int cnt[GMAXN];
  __shared__ int wred[4];
  int g = blockIdx.x;
  int t = threadIdx.x;
  int s = sizes[g];
  int off = g_off[g];
  for (int i = t; i < s; i += NT)
    cnt[i] = 2 - (i == 0 ? 1 : 0) - (i == s - 1 ? 1 : 0);
  __syncthreads();
  const int2* re2 = (const int2*)(edges) + (N - B) + off;
  for (int j = t; j < s; j += NT) {
    int2 e = re2[j];
    atomicAdd(&cnt[e.x - off], 1);
    atomicAdd(&cnt[e.y - off], 1);
  }
  __syncthreads();
  int m = 0;
  for (int i = t; i < s; i += NT) m = max(m, cnt[i]);
  #pragma unroll
  for (int o = 32; o > 0; o >>= 1) m = max(m, __shfl_down(m, o, 64));
  if ((t & 63) == 0) wred[t >> 6] = m;
  __syncthreads();
  if (t == 0) {
    m = max(max(wred[0], wred[1]), max(wred[2], wred[3]));
    atomicMax(&g_maxdeg, m);
  }
}

// K3: one block per RANK-PAIR of groups (rank b, rank B-1-b) — pair sums are
// uniform (~2048) so all blocks do equal work. CSR with pre-signed
// position-ordered u entries (phase B = contiguous sum). Segmented sparsemax.
__global__ __launch_bounds__(NT, 4) void k_main(const float* __restrict__ x,
                                                const int* __restrict__ sizes,
                                                const int* __restrict__ edges,
                                                float* __restrict__ out,
                                                int N, int B) {
  __shared__ float yL[CAP];            // y (aliased as int cnt[] during build)
  __shared__ float uE[2 * CAP];        // pre-signed u entries (aliased as cur[])
  __shared__ float uCh[CAP];           // chain-edge u
  __shared__ ushort offL[CAP + 2];     // CSR offsets
  __shared__ float redf[2][8];
  __shared__ int wtot[4];

  int b = blockIdx.x;
  int t = threadIdx.x;
  int lane = t & 63, wid = t >> 6;
  int g1 = g_rank[b];
  int g2i = B - 1 - b;
  int g2 = (g2i != b) ? g_rank[g2i] : -1;
  int s1g = sizes[g1], off1g = g_off[g1];
  int s2g = 0, off2g = 0;
  if (g2 >= 0) { s2g = sizes[g2]; off2g = g_off[g2]; }
  float step = 1.0f / (2.0f * (float)g_maxdeg);
  int nch = N - B;                      // base row of random edges
  int npass = (s1g + s2g <= CAP) ? 1 : 2;

  for (int pass = 0; pass < npass; ++pass) {
    int ss1, oo1, ss2, oo2;
    if (npass == 1) { ss1 = s1g; oo1 = off1g; ss2 = s2g; oo2 = off2g; }
    else { ss1 = pass ? s2g : s1g; oo1 = pass ? off2g : off1g; ss2 = 0; oo2 = 0; }
    int S = ss1 + ss2;
    __syncthreads();

    // ---- random edges -> regs (endpoints local to union, packed a|b<<16)
    uint ab[SLOT];
    #pragma unroll
    for (int k = 0; k < SLOT; ++k) {
      int j = t + k * NT;
      uint pk = 0;
      if (j < S) {
        int2 e;
        if (j < ss1) { e = ((const int2*)edges)[nch + oo1 + j];
                       pk = (uint)(e.x - oo1) | ((uint)(e.y - oo1) << 16); }
        else         { e = ((const int2*)edges)[nch + oo2 + (j - ss1)];
                       pk = (uint)(e.x - oo2 + ss1) | ((uint)(e.y - oo2 + ss1) << 16); }
      }
      ab[k] = pk;
    }
    // ---- x -> regs
    float xr[SLOT];
    #pragma unroll
    for (int k = 0; k < SLOT; ++k) {
      int i = t + k * NT;
      float v = 0.0f;
      if (i < S) v = (i < ss1) ? x[oo1 + i] : x[oo2 + i - ss1];
      xr[k] = v;
    }

    // ---- CSR build over union (random incidences only)
    int* cnt = (int*)yL;
    #pragma unroll
    for (int k = 0; k < SLOT; ++k) { int i = t + k * NT; if (i < S) cnt[i] = 0; }
    __syncthreads();
    #pragma unroll
    for (int k = 0; k < SLOT; ++k) {
      int j = t + k * NT;
      if (j < S) {
        atomicAdd(&cnt[ab[k] & 0xFFFFu], 1);
        atomicAdd(&cnt[ab[k] >> 16], 1);
      }
    }
    __syncthreads();
    // chunked exclusive scan: thread t owns [t*SLOT, t*SLOT+SLOT)
    int c[SLOT];
    int tot = 0;
    #pragma unroll
    for (int k = 0; k < SLOT; ++k) {
      int i = t * SLOT + k;
      int v = (i < S) ? cnt[i] : 0;
      c[k] = tot; tot += v;
    }
    int inc = tot;
    #pragma unroll
    for (int o = 1; o < 64; o <<= 1) {
      int n = __shfl_up(inc, o, 64);
      if (lane >= o) inc += n;
    }
    if (lane == 63) wtot[wid] = inc;
    __syncthreads();
    int wpre = 0;
    #pragma unroll
    for (int w = 0; w < 4; ++w) wpre += (w < wid) ? wtot[w] : 0;
    int basep = wpre + (inc - tot);
    int* cur = (int*)uE;
    #pragma unroll
    for (int k = 0; k < SLOT; ++k) {
      int i = t * SLOT + k;
      if (i < S) { int v = basep + c[k]; offL[i] = (ushort)v; cur[i] = v; }
    }
    if (t == 0) offL[S] = (ushort)(2 * S);
    __syncthreads();
    // fill: record this edge's two entry positions into regs
    uint pw[SLOT];
    #pragma unroll
    for (int k = 0; k < SLOT; ++k) {
      int j = t + k * NT;
      uint v = 0;
      if (j < S) {
        int pa = atomicAdd(&cur[ab[k] & 0xFFFFu], 1);
        int pb = atomicAdd(&cur[ab[k] >> 16], 1);
        v = (uint)pa | ((uint)pb << 16);
      }
      pw[k] = v;
    }
    // hoist CSR ranges (reads offL only; concurrent with fill is safe)
    uint pq[SLOT];
    #pragma unroll
    for (int k = 0; k < SLOT; ++k) {
      int i = t + k * NT;
      uint v = 0;
      if (i < S) { uint p0 = offL[i]; uint n = (uint)offL[i + 1] - p0; v = p0 | (n << 16); }
      pq[k] = v;
    }
    // init y = x, uCh = 0 (yL aliases cnt: safe, cnt no longer read)
    float yreg[SLOT], uC[SLOT], uRr[SLOT];
    #pragma unroll
    for (int k = 0; k < SLOT; ++k) {
      int i = t + k * NT;
      uC[k] = 0.0f; uRr[k] = 0.0f;
      if (i < S) { yL[i] = xr[k]; uCh[i] = 0.0f; }
      yreg[k] = (i < S) ? xr[k] : -1e30f;
    }
    __syncthreads();

    // ---- TV iterations: 2 barriers each, no atomics
    for (int it = 0; it < TVITERS; ++it) {
      bool last = (it == TVITERS - 1);
      // Phase A
      float yn[SLOT], ya[SLOT], yb[SLOT];
      #pragma unroll
      for (int k = 0; k < SLOT; ++k) {
        int i = t + k * NT;
        yn[k] = (i + 1 < S) ? yL[i + 1] : 0.0f;
      }
      #pragma unroll
      for (int k = 0; k < SLOT; ++k) {
        int j = t + k * NT;
        if (j < S) {
          ya[k] = yL[ab[k] & 0xFFFFu];
          yb[k] = yL[ab[k] >> 16];
        }
      }
      #pragma unroll
      for (int k = 0; k < SLOT; ++k) {
        int i = t + k * NT;
        bool ch = (i < S - 1) && (i != ss1 - 1);
        if (ch) {
          float nu = uC[k] + step * (yreg[k] - yn[k]);
          nu = fminf(1.0f, fmaxf(-1.0f, nu));
          uC[k] = nu;
          uCh[i] = nu;
        }
      }
      #pragma unroll
      for (int k = 0; k < SLOT; ++k) {
        int j = t + k * NT;
        if (j < S) {
          float nu = uRr[k] + step * (ya[k] - yb[k]);
          nu = fminf(1.0f, fmaxf(-1.0f, nu));
          uRr[k] = nu;
          uE[pw[k] & 0xFFFFu] = -nu;
          uE[pw[k] >> 16] = nu;
        }
      }
      __syncthreads();
      // Phase B: y = x + chain terms + contiguous pre-signed entry sum
      #pragma unroll
      for (int k = 0; k < SLOT; ++k) {
        int i = t + k * NT;
        if (i < S) {
          float y = xr[k];
          if (i > 0 && i != ss1) y += uCh[i - 1];
          if ((i < S - 1) && (i != ss1 - 1)) y -= uC[k];
          uint p = pq[k] & 0xFFFFu, n = pq[k] >> 16;
          for (uint q = 0; q < n; ++q) y += uE[p + q];
          yreg[k] = y;
          if (!last) yL[i] = y;
        }
      }
      if (!last) __syncthreads();
    }

    // ---- segmented sparsemax (both groups simultaneously)
    float m1 = -1e30f, m2 = -1e30f;
    #pragma unroll
    for (int k = 0; k < SLOT; ++k) {
      int i = t + k * NT;
      if (i < S) { if (i < ss1) m1 = fmaxf(m1, yreg[k]); else m2 = fmaxf(m2, yreg[k]); }
    }
    #pragma unroll
    for (int o = 1; o < 64; o <<= 1) {
      m1 = fmaxf(m1, __shfl_xor(m1, o, 64));
      m2 = fmaxf(m2, __shfl_xor(m2, o, 64));
    }
    if (lane == 0) { redf[0][wid] = m1; redf[0][4 + wid] = m2; }
    __syncthreads();
    m1 = fmaxf(fmaxf(redf[0][0], redf[0][1]), fmaxf(redf[0][2], redf[0][3]));
    m2 = fmaxf(fmaxf(redf[0][4], redf[0][5]), fmaxf(redf[0][6], redf[0][7]));

    float lo1 = m1 - 1.0f, hi1 = m1, lo2 = m2 - 1.0f, hi2 = m2;
    int par = 1;
    for (int r = 0; r < BISECT; ++r) {
      float mid1 = 0.5f * (lo1 + hi1), mid2 = 0.5f * (lo2 + hi2);
      float f1 = 0.0f, f2 = 0.0f;
      #pragma unroll
      for (int k = 0; k < SLOT; ++k) {
        int i = t + k * NT;
        if (i < S) {
          if (i < ss1) f1 += fmaxf(yreg[k] - mid1, 0.0f);
          else         f2 += fmaxf(yreg[k] - mid2, 0.0f);
        }
      }
      #pragma unroll
      for (int o = 1; o < 64; o <<= 1) {
        f1 += __shfl_xor(f1, o, 64);
        f2 += __shfl_xor(f2, o, 64);
      }
      if (lane == 0) { redf[par][wid] = f1; redf[par][4 + wid] = f2; }
      __syncthreads();
      f1 = redf[par][0] + redf[par][1] + redf[par][2] + redf[par][3];
      f2 = redf[par][4] + redf[par][5] + redf[par][6] + redf[par][7];
      par ^= 1;
      if (f1 >= 1.0f) lo1 = mid1; else hi1 = mid1;
      if (f2 >= 1.0f) lo2 = mid2; else hi2 = mid2;
    }
    __syncthreads();   // protect redf reuse below
    // exact refinement on identified supports
    float cf1 = 0.0f, S1 = 0.0f, cf2 = 0.0f, S2 = 0.0f;
    #pragma unroll
    for (int k = 0; k < SLOT; ++k) {
      int i = t + k * NT;
      if (i < S) {
        if (i < ss1) { if (yreg[k] > lo1) { cf1 += 1.0f; S1 += yreg[k]; } }
        else         { if (yreg[k] > lo2) { cf2 += 1.0f; S2 += yreg[k]; } }
      }
    }
    #pragma unroll
    for (int o = 1; o < 64; o <<= 1) {
      cf1 += __shfl_xor(cf1, o, 64);
      S1  += __shfl_xor(S1,  o, 64);
      cf2 += __shfl_xor(cf2, o, 64);
      S2  += __shfl_xor(S2,  o, 64);
    }
    float* redflat = (float*)redf;
    if (lane == 0) {
      redflat[wid] = cf1; redflat[4 + wid] = S1;
      redflat[8 + wid] = cf2; redflat[12 + wid] = S2;
    }
    __syncthreads();
    cf1 = redflat[0] + redflat[1] + redflat[2] + redflat[3];
    S1  = redflat[4] + redflat[5] + redflat[6] + redflat[7];
    cf2 = redflat[8] + redflat[9] + redflat[10] + redflat[11];
    S2  = redflat[12] + redflat[13] + redflat[14] + redflat[15];
    float tau1 = (S1 - 1.0f) / cf1;
    float tau2 = (cf2 > 0.0f) ? (S2 - 1.0f) / cf2 : 0.0f;

    float sf1 = (float)ss1, sf2 = (float)ss2;
    #pragma unroll
    for (int k = 0; k < SLOT; ++k) {
      int i = t + k * NT;
      if (i < S) {
        bool in2 = (i >= ss1);
        float tau = in2 ? tau2 : tau1;
        float sf = in2 ? sf2 : sf1;
        int o = in2 ? (oo2 + i - ss1) : (oo1 + i);
        out[o] = fmaxf(yreg[k] - tau, 0.0f) * sf;
      }
    }
  }
}

extern "C" void kernel_launch(void* const* d_in, const int* in_sizes, int n_in,
                              void* d_out, int out_size, void* d_ws, size_t ws_size,
                              hipStream_t stream) {
  const float* x = (const float*)d_in[0];
  const int* sizes = (const int*)d_in[1];
  const int* edges = (const int*)d_in[2];
  float* out = (float*)d_out;
  int N = in_sizes[0];
  int B = in_sizes[1];
  (void)d_ws; (void)ws_size; (void)n_in; (void)out_size;

  k_scan<<<1, NT, 0, stream>>>(sizes, B);
  k_deg<<<B, NT, 0, stream>>>(sizes, edges, N, B);
  int nb = (B + 1) / 2;
  k_main<<<nb, NT, 0, stream>>>(x, sizes, edges, out, N, B);
}